// Round 4
// baseline (209.715 us; speedup 1.0000x reference)
//
#include <hip/hip_runtime.h>

typedef _Float16 h8 __attribute__((ext_vector_type(8)));
typedef _Float16 h4 __attribute__((ext_vector_type(4)));
typedef float f4 __attribute__((ext_vector_type(4)));

#define B_ 4096
#define T_ 64
#define I_ 8
#define H_ 128

// LDS layout (bytes). Total 147456 <= 163840.
#define WC0_OFF 0            // [512 packed-gates][128 k] fp16, XOR-swizzled = 131072
#define H0_OFF  131072       // 2 x [16 batch][128 u] fp16, swizzled        = 8192
#define H1_OFF  139264       // 2 x [16][128]                               = 8192
#define LDS_TOTAL 147456

#define LOG2E    1.4426950408889634f
#define TWOLOG2E 2.8853900817779268f

// gates arrive pre-scaled by log2e (i,f,o) / 2*log2e (g)
__device__ __forceinline__ float sigm2_(float v) {
    return __builtin_amdgcn_rcpf(1.f + exp2f(-v));
}
__device__ __forceinline__ float tanh2_(float v) {
    return 1.f - 2.f * __builtin_amdgcn_rcpf(exp2f(v) + 1.f);
}
__device__ __forceinline__ float tanhn_(float v) {   // natural units (for c)
    return 1.f - 2.f * __builtin_amdgcn_rcpf(exp2f(TWOLOG2E * v) + 1.f);
}

// Packed gate order: packed row p = w*64 + j*16 + r, r = G4*4 + q.
// p -> (u = w*16 + G4*4 + j, gate q), original row gs = q*128 + u.
// Thread (w,G4,c16) owns u = w*16+G4*4+{0..3} for batch c16 -> one ds_write_b64.
// NOTE __launch_bounds__(512, 1): LDS already caps at 1 block/CU; second arg=1
// lifts the VGPR cap to the full per-wave budget so wc1 (128 VGPRs) is resident
// (with arg=2 hipcc capped at 128 VGPRs and spilled wc1 to scratch -> L2
// reloads every step dominated the runtime).
__global__ __launch_bounds__(512, 1) void lstm_fused_kernel(
    const float* __restrict__ x,
    const float* __restrict__ Wih0, const float* __restrict__ Whh0,
    const float* __restrict__ bih0, const float* __restrict__ bhh0,
    const float* __restrict__ Wih1, const float* __restrict__ Whh1,
    const float* __restrict__ bih1, const float* __restrict__ bhh1,
    const float* __restrict__ Wd1, const float* __restrict__ bd1,
    const float* __restrict__ Wd2, const float* __restrict__ bd2,
    float* __restrict__ out)
{
    __shared__ __align__(16) unsigned char lds[LDS_TOTAL];
    const int tid = threadIdx.x;
    const int w   = tid >> 6;
    const int l   = tid & 63;
    const int c16 = l & 15;
    const int G4  = l >> 4;
    const int rowbase = blockIdx.x * 16;
    const int swzl = (l & 7) << 4;

    // ---- init: Wc0 (packed order, prescaled, fp16, swizzled) -> LDS
    {
        const int p  = tid;
        const int q  = p & 3;
        const int gs = q * H_ + (p >> 6) * 16 + ((p >> 2) & 3) * 4 + ((p >> 4) & 3);
        const float sc = (q == 2) ? TWOLOG2E : LOG2E;
        const float* src = Whh0 + (size_t)gs * H_;
        const int swz = (p & 7) << 4;
        unsigned char* dst = lds + WC0_OFF + p * 256;
#pragma unroll
        for (int kb = 0; kb < 16; kb++) {
            float4 f0 = *(const float4*)(src + kb * 8);
            float4 f1 = *(const float4*)(src + kb * 8 + 4);
            h8 v;
            v[0]=(_Float16)(f0.x*sc); v[1]=(_Float16)(f0.y*sc);
            v[2]=(_Float16)(f0.z*sc); v[3]=(_Float16)(f0.w*sc);
            v[4]=(_Float16)(f1.x*sc); v[5]=(_Float16)(f1.y*sc);
            v[6]=(_Float16)(f1.z*sc); v[7]=(_Float16)(f1.w*sc);
            *(h8*)(dst + ((kb * 16) ^ swz)) = v;
        }
    }
    // zero the t=0 read buffers (index 1)
    {
        f4 z = {0.f, 0.f, 0.f, 0.f};
        if (tid < 256) *(f4*)(lds + H0_OFF + 4096 + tid * 16) = z;
        else           *(f4*)(lds + H1_OFF + 4096 + (tid - 256) * 16) = z;
    }

    // ---- init: Wc1 A-frags + x-weight/bias frag (K=16) + L1 bias, all prescaled
    h8 wc1[4][8];
    h4 ax16[4];
    f4 b1[4];
    {
        const int rq = c16 & 3;
        const float sc1 = (rq == 2) ? TWOLOG2E : LOG2E;
#pragma unroll
        for (int j = 0; j < 4; j++) {
            const int gs = rq * H_ + w * 16 + (c16 >> 2) * 4 + j;
#pragma unroll
            for (int ks = 0; ks < 8; ks++) {
                const int k0 = ks * 32 + G4 * 8;
                const float* src = (k0 < 128) ? (Whh1 + (size_t)gs * H_ + k0)
                                              : (Wih1 + (size_t)gs * H_ + (k0 - 128));
                float4 f0 = *(const float4*)src;
                float4 f1 = *(const float4*)(src + 4);
                h8 v;
                v[0]=(_Float16)(f0.x*sc1); v[1]=(_Float16)(f0.y*sc1);
                v[2]=(_Float16)(f0.z*sc1); v[3]=(_Float16)(f0.w*sc1);
                v[4]=(_Float16)(f1.x*sc1); v[5]=(_Float16)(f1.y*sc1);
                v[6]=(_Float16)(f1.z*sc1); v[7]=(_Float16)(f1.w*sc1);
                wc1[j][ks] = v;
            }
            h4 a;
#pragma unroll
            for (int e = 0; e < 4; e++) {
                const int k = G4 * 4 + e;
                float val = 0.f;
                if (k < 8)       val = Wih0[(size_t)gs * I_ + k] * sc1;
                else if (k == 8) val = (bih0[gs] + bhh0[gs]) * sc1;
                a[e] = (_Float16)val;
            }
            ax16[j] = a;
            f4 bb;
#pragma unroll
            for (int q2 = 0; q2 < 4; q2++) {
                const int gs2 = q2 * H_ + w * 16 + G4 * 4 + j;
                bb[q2] = (bih1[gs2] + bhh1[gs2]) * ((q2 == 2) ? TWOLOG2E : LOG2E);
            }
            b1[j] = bb;
        }
    }

    const float* xrow = x + (size_t)(rowbase + c16) * T_ * I_;
    float4 xf0 = *(const float4*)(xrow);
    float4 xf1 = *(const float4*)(xrow + 4);

    float c0r[4] = {0.f, 0.f, 0.f, 0.f};
    float c1r[4] = {0.f, 0.f, 0.f, 0.f};

    __syncthreads();

    int cur = 0;
    for (int t = 0; t < T_; t++) {
        // B-frag (K=16) for the x/bias chunk: k<8 = x_t, k=8 -> 1.0
        h4 bx;
        bx[0] = (_Float16)0.f; bx[1] = (_Float16)0.f;
        bx[2] = (_Float16)0.f; bx[3] = (_Float16)0.f;
        if (G4 == 0) {
            bx[0]=(_Float16)xf0.x; bx[1]=(_Float16)xf0.y;
            bx[2]=(_Float16)xf0.z; bx[3]=(_Float16)xf0.w;
        } else if (G4 == 1) {
            bx[0]=(_Float16)xf1.x; bx[1]=(_Float16)xf1.y;
            bx[2]=(_Float16)xf1.z; bx[3]=(_Float16)xf1.w;
        } else if (G4 == 2) {
            bx[0] = (_Float16)1.f;
        }
        if (t < T_ - 1) {
            xf0 = *(const float4*)(xrow + (t + 1) * 8);
            xf1 = *(const float4*)(xrow + (t + 1) * 8 + 4);
        }

        // ---------------- layer 0 MFMAs (h0_old + x/bias)
        f4 acc0[4], acc1[4];
        {
            f4 z = {0.f, 0.f, 0.f, 0.f};
#pragma unroll
            for (int j = 0; j < 4; j++) acc0[j] = z;
        }
        const unsigned char* h0rd = lds + H0_OFF + (cur ^ 1) * 4096;
#pragma unroll
        for (int ks = 0; ks < 4; ks++) {
            h8 b = *(const h8*)(h0rd + ((c16 * 256 + ks * 64 + G4 * 16) ^ swzl));
#pragma unroll
            for (int j = 0; j < 4; j++) {
                h8 a = *(const h8*)(lds + WC0_OFF + (w * 64 + j * 16 + c16) * 256
                                    + ((ks * 64 + G4 * 16) ^ swzl));
                acc0[j] = __builtin_amdgcn_mfma_f32_16x16x32_f16(a, b, acc0[j], 0, 0, 0);
            }
        }
#pragma unroll
        for (int j = 0; j < 4; j++)
            acc0[j] = __builtin_amdgcn_mfma_f32_16x16x16f16(ax16[j], bx, acc0[j], 0, 0, 0);

        // ---------------- layer 1 part A (h1_old-dependent; overlaps L0 epilogue)
        const unsigned char* h1rd = lds + H1_OFF + (cur ^ 1) * 4096;
#pragma unroll
        for (int j = 0; j < 4; j++) acc1[j] = b1[j];
#pragma unroll
        for (int ks = 0; ks < 4; ks++) {
            h8 b = *(const h8*)(h1rd + ((c16 * 256 + ks * 64 + G4 * 16) ^ swzl));
#pragma unroll
            for (int j = 0; j < 4; j++)
                acc1[j] = __builtin_amdgcn_mfma_f32_16x16x32_f16(wc1[j][ks], b, acc1[j], 0, 0, 0);
        }

        // ---------------- layer 0 epilogue -> h0[cur]
        unsigned char* h0wr = lds + H0_OFF + cur * 4096;
        {
            h4 hv;
#pragma unroll
            for (int j = 0; j < 4; j++) {
                const float vi = sigm2_(acc0[j][0]);
                const float vf = sigm2_(acc0[j][1]);
                const float vg = tanh2_(acc0[j][2]);
                const float vo = sigm2_(acc0[j][3]);
                const float cn = vf * c0r[j] + vi * vg;
                c0r[j] = cn;
                hv[j] = (_Float16)(vo * tanhn_(cn));
            }
            *(h4*)(h0wr + ((c16 * 256 + w * 32 + G4 * 8) ^ swzl)) = hv;
        }

        __syncthreads();   // barrier A: h0_new visible

        // ---------------- layer 1 part B (h0_new-dependent)
        const unsigned char* h0n = lds + H0_OFF + cur * 4096;
#pragma unroll
        for (int ks = 0; ks < 4; ks++) {
            h8 b = *(const h8*)(h0n + ((c16 * 256 + ks * 64 + G4 * 16) ^ swzl));
#pragma unroll
            for (int j = 0; j < 4; j++)
                acc1[j] = __builtin_amdgcn_mfma_f32_16x16x32_f16(wc1[j][ks + 4], b, acc1[j], 0, 0, 0);
        }
        unsigned char* h1wr = lds + H1_OFF + cur * 4096;
        {
            h4 hv;
#pragma unroll
            for (int j = 0; j < 4; j++) {
                const float vi = sigm2_(acc1[j][0]);
                const float vf = sigm2_(acc1[j][1]);
                const float vg = tanh2_(acc1[j][2]);
                const float vo = sigm2_(acc1[j][3]);
                const float cn = vf * c1r[j] + vi * vg;
                c1r[j] = cn;
                hv[j] = (_Float16)(vo * tanhn_(cn));
            }
            *(h4*)(h1wr + ((c16 * 256 + w * 32 + G4 * 8) ^ swzl)) = hv;
        }

        __syncthreads();   // barrier B: cross-step ordering for the part-A hoist
        cur ^= 1;
    }

    // ---------------- head
    if (tid < 128) {
        const int r = tid >> 3, part = tid & 7;
        const unsigned char* h1f = lds + H1_OFF + 4096;   // t=63 wrote buffer 1
        const int rswz = (r & 7) << 4;
        float s0 = 0.f, s1 = 0.f, s2 = 0.f, s3 = 0.f, s4 = 0.f;
#pragma unroll
        for (int kk = 0; kk < 16; kk++) {
            const int k = part * 16 + kk;
            float a = (float)*(const _Float16*)(h1f + ((r * 256 + k * 2) ^ rswz));
            a = fmaxf(a, 0.f);
            s0 += a * Wd1[0 * H_ + k];
            s1 += a * Wd1[1 * H_ + k];
            s2 += a * Wd1[2 * H_ + k];
            s3 += a * Wd1[3 * H_ + k];
            s4 += a * Wd1[4 * H_ + k];
        }
#pragma unroll
        for (int m = 1; m < 8; m <<= 1) {
            s0 += __shfl_xor(s0, m);
            s1 += __shfl_xor(s1, m);
            s2 += __shfl_xor(s2, m);
            s3 += __shfl_xor(s3, m);
            s4 += __shfl_xor(s4, m);
        }
        if (part == 0) {
            float o = bd2[0];
            o += fmaxf(s0 + bd1[0], 0.f) * Wd2[0];
            o += fmaxf(s1 + bd1[1], 0.f) * Wd2[1];
            o += fmaxf(s2 + bd1[2], 0.f) * Wd2[2];
            o += fmaxf(s3 + bd1[3], 0.f) * Wd2[3];
            o += fmaxf(s4 + bd1[4], 0.f) * Wd2[4];
            out[rowbase + r] = o;
        }
    }
}

extern "C" void kernel_launch(void* const* d_in, const int* in_sizes, int n_in,
                              void* d_out, int out_size, void* d_ws, size_t ws_size,
                              hipStream_t stream)
{
    const float* x    = (const float*)d_in[0];
    const float* Wih0 = (const float*)d_in[1];
    const float* Whh0 = (const float*)d_in[2];
    const float* bih0 = (const float*)d_in[3];
    const float* bhh0 = (const float*)d_in[4];
    const float* Wih1 = (const float*)d_in[5];
    const float* Whh1 = (const float*)d_in[6];
    const float* bih1 = (const float*)d_in[7];
    const float* bhh1 = (const float*)d_in[8];
    const float* Wd1  = (const float*)d_in[9];
    const float* bd1  = (const float*)d_in[10];
    const float* Wd2  = (const float*)d_in[11];
    const float* bd2  = (const float*)d_in[12];

    lstm_fused_kernel<<<B_ / 16, 512, 0, stream>>>(
        x, Wih0, Whh0, bih0, bhh0, Wih1, Whh1, bih1, bhh1,
        Wd1, bd1, Wd2, bd2, (float*)d_out);
}

// Round 5
// 209.433 us; speedup vs baseline: 1.0013x; 1.0013x over previous
//
#include <hip/hip_runtime.h>

typedef _Float16 h8 __attribute__((ext_vector_type(8)));
typedef _Float16 h4 __attribute__((ext_vector_type(4)));
typedef float f4 __attribute__((ext_vector_type(4)));

#define B_ 4096
#define T_ 64
#define I_ 8
#define H_ 128

// LDS layout (bytes). Total 147456 <= 163840.
#define WC0_OFF 0            // [512 packed-gates][128 k] fp16, XOR-swizzled = 131072
#define H0_OFF  131072       // 2 x [16 batch][128 u] fp16, swizzled        = 8192
#define H1_OFF  139264       // 2 x [16][128]                               = 8192
#define LDS_TOTAL 147456

#define LOG2E    1.4426950408889634f
#define TWOLOG2E 2.8853900817779268f

// gates arrive pre-scaled by log2e (i,f,o) / 2*log2e (g)
__device__ __forceinline__ float sigm2_(float v) {
    return __builtin_amdgcn_rcpf(1.f + exp2f(-v));
}
__device__ __forceinline__ float tanh2_(float v) {
    return 1.f - 2.f * __builtin_amdgcn_rcpf(exp2f(v) + 1.f);
}
__device__ __forceinline__ float tanhn_(float v) {   // natural units (for c)
    return 1.f - 2.f * __builtin_amdgcn_rcpf(exp2f(TWOLOG2E * v) + 1.f);
}

// Packed gate order: packed row p = w*64 + j*16 + r, r = G4*4 + q.
// p -> (u = w*16 + G4*4 + j, gate q), original row gs = q*128 + u.
// Thread (w,G4,c16) owns u = w*16+G4*4+{0..3} for batch c16 -> one ds_write_b64.
//
// REGISTER CAP: __launch_bounds__'s 2nd arg is only a LOWER bound on
// waves/EU -> allocator kept its default 4-waves/EU target (128 VGPRs) and
// spilled wc1 (~100 regs) to scratch; per-step L2 reloads were the 200 µs
// wall (WRITE_SIZE 28.7 MB of spill stores, dur invariant to all edits).
// amdgpu_waves_per_eu(2,2) pins min=max=2 waves/EU -> 256-VGPR budget.
// Runtime occupancy is 2 waves/SIMD anyway (512 thr, 147 KB LDS = 1 blk/CU),
// so nothing is lost.
__global__ __attribute__((amdgpu_waves_per_eu(2, 2))) __launch_bounds__(512)
void lstm_fused_kernel(
    const float* __restrict__ x,
    const float* __restrict__ Wih0, const float* __restrict__ Whh0,
    const float* __restrict__ bih0, const float* __restrict__ bhh0,
    const float* __restrict__ Wih1, const float* __restrict__ Whh1,
    const float* __restrict__ bih1, const float* __restrict__ bhh1,
    const float* __restrict__ Wd1, const float* __restrict__ bd1,
    const float* __restrict__ Wd2, const float* __restrict__ bd2,
    float* __restrict__ out)
{
    __shared__ __align__(16) unsigned char lds[LDS_TOTAL];
    const int tid = threadIdx.x;
    const int w   = tid >> 6;
    const int l   = tid & 63;
    const int c16 = l & 15;
    const int G4  = l >> 4;
    const int rowbase = blockIdx.x * 16;
    const int swzl = (l & 7) << 4;

    // ---- init: Wc0 (packed order, prescaled, fp16, swizzled) -> LDS
    {
        const int p  = tid;
        const int q  = p & 3;
        const int gs = q * H_ + (p >> 6) * 16 + ((p >> 2) & 3) * 4 + ((p >> 4) & 3);
        const float sc = (q == 2) ? TWOLOG2E : LOG2E;
        const float* src = Whh0 + (size_t)gs * H_;
        const int swz = (p & 7) << 4;
        unsigned char* dst = lds + WC0_OFF + p * 256;
#pragma unroll
        for (int kb = 0; kb < 16; kb++) {
            float4 f0 = *(const float4*)(src + kb * 8);
            float4 f1 = *(const float4*)(src + kb * 8 + 4);
            h8 v;
            v[0]=(_Float16)(f0.x*sc); v[1]=(_Float16)(f0.y*sc);
            v[2]=(_Float16)(f0.z*sc); v[3]=(_Float16)(f0.w*sc);
            v[4]=(_Float16)(f1.x*sc); v[5]=(_Float16)(f1.y*sc);
            v[6]=(_Float16)(f1.z*sc); v[7]=(_Float16)(f1.w*sc);
            *(h8*)(dst + ((kb * 16) ^ swz)) = v;
        }
    }
    // zero the t=0 read buffers (index 1)
    {
        f4 z = {0.f, 0.f, 0.f, 0.f};
        if (tid < 256) *(f4*)(lds + H0_OFF + 4096 + tid * 16) = z;
        else           *(f4*)(lds + H1_OFF + 4096 + (tid - 256) * 16) = z;
    }

    // ---- init: Wc1 A-frags + x-weight/bias frag (K=16) + L1 bias, all prescaled
    h8 wc1[4][8];
    h4 ax16[4];
    f4 b1[4];
    {
        const int rq = c16 & 3;
        const float sc1 = (rq == 2) ? TWOLOG2E : LOG2E;
#pragma unroll
        for (int j = 0; j < 4; j++) {
            const int gs = rq * H_ + w * 16 + (c16 >> 2) * 4 + j;
#pragma unroll
            for (int ks = 0; ks < 8; ks++) {
                const int k0 = ks * 32 + G4 * 8;
                const float* src = (k0 < 128) ? (Whh1 + (size_t)gs * H_ + k0)
                                              : (Wih1 + (size_t)gs * H_ + (k0 - 128));
                float4 f0 = *(const float4*)src;
                float4 f1 = *(const float4*)(src + 4);
                h8 v;
                v[0]=(_Float16)(f0.x*sc1); v[1]=(_Float16)(f0.y*sc1);
                v[2]=(_Float16)(f0.z*sc1); v[3]=(_Float16)(f0.w*sc1);
                v[4]=(_Float16)(f1.x*sc1); v[5]=(_Float16)(f1.y*sc1);
                v[6]=(_Float16)(f1.z*sc1); v[7]=(_Float16)(f1.w*sc1);
                wc1[j][ks] = v;
            }
            h4 a;
#pragma unroll
            for (int e = 0; e < 4; e++) {
                const int k = G4 * 4 + e;
                float val = 0.f;
                if (k < 8)       val = Wih0[(size_t)gs * I_ + k] * sc1;
                else if (k == 8) val = (bih0[gs] + bhh0[gs]) * sc1;
                a[e] = (_Float16)val;
            }
            ax16[j] = a;
            f4 bb;
#pragma unroll
            for (int q2 = 0; q2 < 4; q2++) {
                const int gs2 = q2 * H_ + w * 16 + G4 * 4 + j;
                bb[q2] = (bih1[gs2] + bhh1[gs2]) * ((q2 == 2) ? TWOLOG2E : LOG2E);
            }
            b1[j] = bb;
        }
    }

    const float* xrow = x + (size_t)(rowbase + c16) * T_ * I_;
    float4 xf0 = *(const float4*)(xrow);
    float4 xf1 = *(const float4*)(xrow + 4);

    float c0r[4] = {0.f, 0.f, 0.f, 0.f};
    float c1r[4] = {0.f, 0.f, 0.f, 0.f};

    __syncthreads();

    int cur = 0;
    for (int t = 0; t < T_; t++) {
        // B-frag (K=16) for the x/bias chunk: k<8 = x_t, k=8 -> 1.0
        h4 bx;
        bx[0] = (_Float16)0.f; bx[1] = (_Float16)0.f;
        bx[2] = (_Float16)0.f; bx[3] = (_Float16)0.f;
        if (G4 == 0) {
            bx[0]=(_Float16)xf0.x; bx[1]=(_Float16)xf0.y;
            bx[2]=(_Float16)xf0.z; bx[3]=(_Float16)xf0.w;
        } else if (G4 == 1) {
            bx[0]=(_Float16)xf1.x; bx[1]=(_Float16)xf1.y;
            bx[2]=(_Float16)xf1.z; bx[3]=(_Float16)xf1.w;
        } else if (G4 == 2) {
            bx[0] = (_Float16)1.f;
        }
        if (t < T_ - 1) {
            xf0 = *(const float4*)(xrow + (t + 1) * 8);
            xf1 = *(const float4*)(xrow + (t + 1) * 8 + 4);
        }

        // ---------------- layer 0 MFMAs (h0_old + x/bias)
        f4 acc0[4], acc1[4];
        {
            f4 z = {0.f, 0.f, 0.f, 0.f};
#pragma unroll
            for (int j = 0; j < 4; j++) acc0[j] = z;
        }
        const unsigned char* h0rd = lds + H0_OFF + (cur ^ 1) * 4096;
#pragma unroll
        for (int ks = 0; ks < 4; ks++) {
            h8 b = *(const h8*)(h0rd + ((c16 * 256 + ks * 64 + G4 * 16) ^ swzl));
#pragma unroll
            for (int j = 0; j < 4; j++) {
                h8 a = *(const h8*)(lds + WC0_OFF + (w * 64 + j * 16 + c16) * 256
                                    + ((ks * 64 + G4 * 16) ^ swzl));
                acc0[j] = __builtin_amdgcn_mfma_f32_16x16x32_f16(a, b, acc0[j], 0, 0, 0);
            }
        }
#pragma unroll
        for (int j = 0; j < 4; j++)
            acc0[j] = __builtin_amdgcn_mfma_f32_16x16x16f16(ax16[j], bx, acc0[j], 0, 0, 0);

        // ---------------- layer 1 part A (h1_old-dependent; overlaps L0 epilogue)
        const unsigned char* h1rd = lds + H1_OFF + (cur ^ 1) * 4096;
#pragma unroll
        for (int j = 0; j < 4; j++) acc1[j] = b1[j];
#pragma unroll
        for (int ks = 0; ks < 4; ks++) {
            h8 b = *(const h8*)(h1rd + ((c16 * 256 + ks * 64 + G4 * 16) ^ swzl));
#pragma unroll
            for (int j = 0; j < 4; j++)
                acc1[j] = __builtin_amdgcn_mfma_f32_16x16x32_f16(wc1[j][ks], b, acc1[j], 0, 0, 0);
        }

        // ---------------- layer 0 epilogue -> h0[cur]
        unsigned char* h0wr = lds + H0_OFF + cur * 4096;
        {
            h4 hv;
#pragma unroll
            for (int j = 0; j < 4; j++) {
                const float vi = sigm2_(acc0[j][0]);
                const float vf = sigm2_(acc0[j][1]);
                const float vg = tanh2_(acc0[j][2]);
                const float vo = sigm2_(acc0[j][3]);
                const float cn = vf * c0r[j] + vi * vg;
                c0r[j] = cn;
                hv[j] = (_Float16)(vo * tanhn_(cn));
            }
            *(h4*)(h0wr + ((c16 * 256 + w * 32 + G4 * 8) ^ swzl)) = hv;
        }

        __syncthreads();   // barrier A: h0_new visible

        // ---------------- layer 1 part B (h0_new-dependent)
        const unsigned char* h0n = lds + H0_OFF + cur * 4096;
#pragma unroll
        for (int ks = 0; ks < 4; ks++) {
            h8 b = *(const h8*)(h0n + ((c16 * 256 + ks * 64 + G4 * 16) ^ swzl));
#pragma unroll
            for (int j = 0; j < 4; j++)
                acc1[j] = __builtin_amdgcn_mfma_f32_16x16x32_f16(wc1[j][ks + 4], b, acc1[j], 0, 0, 0);
        }
        unsigned char* h1wr = lds + H1_OFF + cur * 4096;
        {
            h4 hv;
#pragma unroll
            for (int j = 0; j < 4; j++) {
                const float vi = sigm2_(acc1[j][0]);
                const float vf = sigm2_(acc1[j][1]);
                const float vg = tanh2_(acc1[j][2]);
                const float vo = sigm2_(acc1[j][3]);
                const float cn = vf * c1r[j] + vi * vg;
                c1r[j] = cn;
                hv[j] = (_Float16)(vo * tanhn_(cn));
            }
            *(h4*)(h1wr + ((c16 * 256 + w * 32 + G4 * 8) ^ swzl)) = hv;
        }

        __syncthreads();   // barrier B: cross-step ordering for the part-A hoist
        cur ^= 1;
    }

    // ---------------- head
    if (tid < 128) {
        const int r = tid >> 3, part = tid & 7;
        const unsigned char* h1f = lds + H1_OFF + 4096;   // t=63 wrote buffer 1
        const int rswz = (r & 7) << 4;
        float s0 = 0.f, s1 = 0.f, s2 = 0.f, s3 = 0.f, s4 = 0.f;
#pragma unroll
        for (int kk = 0; kk < 16; kk++) {
            const int k = part * 16 + kk;
            float a = (float)*(const _Float16*)(h1f + ((r * 256 + k * 2) ^ rswz));
            a = fmaxf(a, 0.f);
            s0 += a * Wd1[0 * H_ + k];
            s1 += a * Wd1[1 * H_ + k];
            s2 += a * Wd1[2 * H_ + k];
            s3 += a * Wd1[3 * H_ + k];
            s4 += a * Wd1[4 * H_ + k];
        }
#pragma unroll
        for (int m = 1; m < 8; m <<= 1) {
            s0 += __shfl_xor(s0, m);
            s1 += __shfl_xor(s1, m);
            s2 += __shfl_xor(s2, m);
            s3 += __shfl_xor(s3, m);
            s4 += __shfl_xor(s4, m);
        }
        if (part == 0) {
            float o = bd2[0];
            o += fmaxf(s0 + bd1[0], 0.f) * Wd2[0];
            o += fmaxf(s1 + bd1[1], 0.f) * Wd2[1];
            o += fmaxf(s2 + bd1[2], 0.f) * Wd2[2];
            o += fmaxf(s3 + bd1[3], 0.f) * Wd2[3];
            o += fmaxf(s4 + bd1[4], 0.f) * Wd2[4];
            out[rowbase + r] = o;
        }
    }
}

extern "C" void kernel_launch(void* const* d_in, const int* in_sizes, int n_in,
                              void* d_out, int out_size, void* d_ws, size_t ws_size,
                              hipStream_t stream)
{
    const float* x    = (const float*)d_in[0];
    const float* Wih0 = (const float*)d_in[1];
    const float* Whh0 = (const float*)d_in[2];
    const float* bih0 = (const float*)d_in[3];
    const float* bhh0 = (const float*)d_in[4];
    const float* Wih1 = (const float*)d_in[5];
    const float* Whh1 = (const float*)d_in[6];
    const float* bih1 = (const float*)d_in[7];
    const float* bhh1 = (const float*)d_in[8];
    const float* Wd1  = (const float*)d_in[9];
    const float* bd1  = (const float*)d_in[10];
    const float* Wd2  = (const float*)d_in[11];
    const float* bd2  = (const float*)d_in[12];

    lstm_fused_kernel<<<B_ / 16, 512, 0, stream>>>(
        x, Wih0, Whh0, bih0, bhh0, Wih1, Whh1, bih1, bhh1,
        Wd1, bd1, Wd2, bd2, (float*)d_out);
}